// Round 1
// baseline (516.803 us; speedup 1.0000x reference)
//
#include <hip/hip_runtime.h>
#include <cstdint>
#include <cstddef>

// Problem constants (fixed by reference)
#define NR   268
#define NB   256
#define NN   (NR*NB)        // 68608 nodes
#define IC   256
#define OC   64
#define DEG  32
#define EPG  (NR*DEG)       // 8576 edges per graph
#define NE   (NN*DEG)       // 2195456 edges
#define KK   214            // top-k per graph

// d_out layout (floats, concatenated outputs)
#define XP_OFF 0            // x_pooled  (256*214, 64)
#define BP_OFF 3506176      // batch_pooled (256*214)
#define SC_OFF 3560960      // scores (68608)
#define PM_OFF 3629568      // perm (256*214)

// workspace layout (float offsets)
#define WS_ROIK 0           // 268*256*64
#define WS_XT   4390912     // 68608*64
#define WS_HB   8781824     // 68608*64  (post-LN h; pre-LN v transiently)
#define WS_META 13172736    // E float2 = 2E floats (src,attr in CSR-by-dst order)
#define WS_ROWS 17563648    // 256*(268+1) uint32 row starts

// ---------------------------------------------------------------------------
// K1: cw = softmax(roi_community); roi_k[r] = sum_c cw[c] * basis[c]
// ---------------------------------------------------------------------------
__global__ __launch_bounds__(256) void k_roik(const float* __restrict__ rc,
                                              const float* __restrict__ basis,
                                              float* __restrict__ roik) {
    int r = blockIdx.x;
    float c[7];
    float m = -1e30f;
#pragma unroll
    for (int j = 0; j < 7; ++j) { c[j] = rc[r*7 + j]; m = fmaxf(m, c[j]); }
    float s = 0.f;
#pragma unroll
    for (int j = 0; j < 7; ++j) { c[j] = expf(c[j] - m); s += c[j]; }
    float inv = 1.f / s;
#pragma unroll
    for (int j = 0; j < 7; ++j) c[j] *= inv;
    for (int idx = threadIdx.x; idx < IC*OC; idx += 256) {
        float acc = 0.f;
#pragma unroll
        for (int j = 0; j < 7; ++j) acc = fmaf(c[j], basis[j*IC*OC + idx], acc);
        roik[(size_t)r*IC*OC + idx] = acc;
    }
}

// ---------------------------------------------------------------------------
// K2: xt[n] = x[n] @ roi_k[n%NR].  block = ROI r, lane = graph g.
// roi_k row values are wave-uniform -> compiler emits s_loads; x row per lane.
// ---------------------------------------------------------------------------
__global__ __launch_bounds__(256) void k_xt(const float* __restrict__ x,
                                            const float* __restrict__ roik,
                                            float* __restrict__ xt) {
    int r = blockIdx.x;
    int g = threadIdx.x;                    // 0..255 graph
    size_t n = (size_t)g * NR + r;
    const float* __restrict__ xrow = x + n * IC;
    const float* __restrict__ wk = roik + (size_t)r * (IC*OC);
    float acc[OC];
#pragma unroll
    for (int o = 0; o < OC; ++o) acc[o] = 0.f;
    float4 xv = *(const float4*)xrow;
    for (int i0 = 0; i0 < IC; i0 += 4) {
        float4 nxt = xv;
        if (i0 + 4 < IC) nxt = *(const float4*)(xrow + i0 + 4);
        float xs0 = xv.x, xs1 = xv.y, xs2 = xv.z, xs3 = xv.w;
#pragma unroll
        for (int o = 0; o < OC; ++o) {
            float a = acc[o];
            a = fmaf(xs0, wk[(i0+0)*OC + o], a);
            a = fmaf(xs1, wk[(i0+1)*OC + o], a);
            a = fmaf(xs2, wk[(i0+2)*OC + o], a);
            a = fmaf(xs3, wk[(i0+3)*OC + o], a);
            acc[o] = a;
        }
        xv = nxt;
    }
    float* __restrict__ xo = xt + n * OC;
#pragma unroll
    for (int o = 0; o < OC; o += 4) {
        float4 v; v.x = acc[o]; v.y = acc[o+1]; v.z = acc[o+2]; v.w = acc[o+3];
        *(float4*)(xo + o) = v;
    }
}

// ---------------------------------------------------------------------------
// K3: per-graph counting sort of edges by dst; emit (src, attr) in CSR order.
// ---------------------------------------------------------------------------
__global__ __launch_bounds__(256) void k_csr(const int* __restrict__ ei,
                                             const float* __restrict__ ea,
                                             float2* __restrict__ meta,
                                             unsigned int* __restrict__ rows) {
    int g = blockIdx.x;
    __shared__ unsigned int cnt[NR];
    __shared__ unsigned int rs[NR];
    __shared__ unsigned int cur[NR];
    for (int i = threadIdx.x; i < NR; i += 256) cnt[i] = 0u;
    __syncthreads();
    int ebase = g * EPG;
    for (int e = threadIdx.x; e < EPG; e += 256) {
        int ld = ei[NE + ebase + e] - g * NR;
        atomicAdd(&cnt[ld], 1u);
    }
    __syncthreads();
    if (threadIdx.x < 64) {                  // wave 0: exclusive scan of 268
        unsigned run = 0;
        for (int base = 0; base < NR; base += 64) {
            int idx = base + (int)threadIdx.x;
            unsigned v = (idx < NR) ? cnt[idx] : 0u;
            unsigned orig = v;
#pragma unroll
            for (int s = 1; s < 64; s <<= 1) {
                int t = __shfl_up((int)v, (unsigned)s, 64);
                if ((int)threadIdx.x >= s) v += (unsigned)t;
            }
            if (idx < NR) { unsigned ex = run + v - orig; rs[idx] = ex; cur[idx] = ex; }
            run += (unsigned)__shfl((int)v, 63, 64);
        }
    }
    __syncthreads();
    for (int i = threadIdx.x; i < NR + 1; i += 256)
        rows[(size_t)g * (NR + 1) + i] = (i < NR) ? rs[i] : (unsigned)EPG;
    for (int e = threadIdx.x; e < EPG; e += 256) {
        int src = ei[ebase + e];
        int dst = ei[NE + ebase + e];
        float a = ea[ebase + e];
        int ld = dst - g * NR;
        unsigned pos = atomicAdd(&cur[ld], 1u);
        float2 mv; mv.x = __int_as_float(src); mv.y = a;
        meta[(size_t)ebase + pos] = mv;
    }
}

// sigmoid: degree-9 odd Taylor around 0, valid |z| <= 0.6 (data: |z| <= ~0.5)
__device__ __forceinline__ float sgate(float z) {
    if (__builtin_expect(fabsf(z) > 0.6f, 0)) return 1.f / (1.f + expf(-z));
    float z2 = z * z;
    float p = fmaf(z2, 2.1357253e-5f, -2.1081349e-4f);  // c9, c7
    p = fmaf(z2, p, 2.0833333e-3f);                     // c5
    p = fmaf(z2, p, -2.0833334e-2f);                    // c3
    p = fmaf(z2, p, 0.25f);                             // c1
    return fmaf(z, p, 0.5f);
}

// ---------------------------------------------------------------------------
// K4: per-graph: gather-aggregate (edge gates) + self loop + bias + ELU ->
//     LayerNorm -> attention scores -> bitonic top-214 -> pooled outputs.
// block = graph (256 blocks x 512 threads). lane = out-channel o.
// ---------------------------------------------------------------------------
__global__ __launch_bounds__(512) void k_main(
    const float* __restrict__ xt,
    const float2* __restrict__ meta,
    const unsigned int* __restrict__ rows,
    float* __restrict__ hbw,
    const float* __restrict__ ew_w, const float* __restrict__ ew_b,
    const float* __restrict__ conv_bias,
    const float* __restrict__ ln_g, const float* __restrict__ ln_b,
    const float* __restrict__ w1, const float* __restrict__ b1,
    const float* __restrict__ w2, const float* __restrict__ b2,
    float* __restrict__ out)
{
    __shared__ float scl[NR];
    __shared__ unsigned long long keys[512];

    int g = blockIdx.x;
    int tid = threadIdx.x;
    int o = tid & 63, w = tid >> 6;          // 8 waves

    float wo = ew_w[o], bo = ew_b[o], cb = conv_bias[o];
    float sgself = 1.f / (1.f + expf(-(wo + bo)));

    const float2* __restrict__ gm = meta + (size_t)g * EPG;
    const unsigned int* __restrict__ gr = rows + (size_t)g * (NR + 1);

    // ---- phase 1: aggregation + ELU; write v rows to global hbw ----
    for (int r = w; r < NR; r += 8) {
        size_t n = (size_t)g * NR + r;
        unsigned js = gr[r], je = gr[r + 1];
        float acc = xt[n*OC + o] * sgself;   // self loop (attr = 1)
        unsigned j = js;
        for (; j + 4 <= je; j += 4) {
            float2 m0 = gm[j], m1 = gm[j+1], m2 = gm[j+2], m3 = gm[j+3];
            float x0 = xt[(size_t)__float_as_int(m0.x)*OC + o];
            float x1 = xt[(size_t)__float_as_int(m1.x)*OC + o];
            float x2 = xt[(size_t)__float_as_int(m2.x)*OC + o];
            float x3 = xt[(size_t)__float_as_int(m3.x)*OC + o];
            acc = fmaf(x0, sgate(fmaf(m0.y, wo, bo)), acc);
            acc = fmaf(x1, sgate(fmaf(m1.y, wo, bo)), acc);
            acc = fmaf(x2, sgate(fmaf(m2.y, wo, bo)), acc);
            acc = fmaf(x3, sgate(fmaf(m3.y, wo, bo)), acc);
        }
        for (; j < je; ++j) {
            float2 m = gm[j];
            float xv = xt[(size_t)__float_as_int(m.x)*OC + o];
            acc = fmaf(xv, sgate(fmaf(m.y, wo, bo)), acc);
        }
        acc += cb;
        float v = acc > 0.f ? acc : expm1f(acc);   // ELU (alpha=1)
        hbw[n*OC + o] = v;
    }
    __syncthreads();

    // ---- phase 2: LN + scores, lane-per-row (waves 0..4) ----
    if (w < 5) {
        int r = w * 64 + o;
        if (r < NR) {
            size_t n = (size_t)g * NR + r;
            float hv[64];
            float s1 = 0.f;
#pragma unroll
            for (int i = 0; i < 64; i += 4) {
                float4 t4 = *(const float4*)(hbw + n*OC + i);
                hv[i] = t4.x; hv[i+1] = t4.y; hv[i+2] = t4.z; hv[i+3] = t4.w;
            }
#pragma unroll
            for (int i = 0; i < 64; ++i) s1 += hv[i];
            float mu = s1 * (1.f/64.f);
            float s2 = 0.f;
#pragma unroll
            for (int i = 0; i < 64; ++i) { float d = hv[i] - mu; s2 = fmaf(d, d, s2); }
            float rsd = rsqrtf(s2 * (1.f/64.f) + 1e-5f);
#pragma unroll
            for (int i = 0; i < 64; ++i) {
                float h = fmaf((hv[i] - mu) * rsd, ln_g[i], ln_b[i]);
                hv[i] = h;
            }
#pragma unroll
            for (int i = 0; i < 64; i += 4) {
                float4 t4; t4.x = hv[i]; t4.y = hv[i+1]; t4.z = hv[i+2]; t4.w = hv[i+3];
                *(float4*)(hbw + n*OC + i) = t4;
            }
            // scores: t = tanh(h @ W1 + b1); s = t @ w2 + b2
            float t[64];
#pragma unroll
            for (int oo = 0; oo < 64; ++oo) t[oo] = b1[oo];
            for (int i = 0; i < 64; ++i) {
                float hvi = hv[i];
#pragma unroll
                for (int oo = 0; oo < 64; ++oo)
                    t[oo] = fmaf(hvi, w1[i*64 + oo], t[oo]);   // w1 uniform -> s_load
            }
            float sacc = 0.f;
#pragma unroll
            for (int oo = 0; oo < 64; ++oo) {
                float a2 = fminf(fmaxf(2.f * t[oo], -80.f), 80.f);
                float y = expf(a2);
                float th = (y - 1.f) / (y + 1.f);
                sacc = fmaf(th, w2[oo], sacc);
            }
            float sc = sacc + b2[0];
            scl[r] = sc;
            out[SC_OFF + (size_t)g * NR + r] = sc;
        }
    }
    __syncthreads();

    // ---- phase 3: bitonic top-K. key = ordered(score) << 32 | ~index ----
    {
        unsigned long long key = 0ull;
        if (tid < NR) {
            unsigned ub = __float_as_uint(scl[tid]);
            unsigned ou = (ub & 0x80000000u) ? ~ub : (ub | 0x80000000u);
            key = (((unsigned long long)ou) << 32) |
                  (unsigned long long)(0xFFFFFFFFu - (unsigned)tid);
        }
        keys[tid] = key;
    }
    for (int kk = 2; kk <= 512; kk <<= 1) {
        for (int j = kk >> 1; j > 0; j >>= 1) {
            __syncthreads();
            int ixj = tid ^ j;
            if (ixj > tid) {
                unsigned long long a = keys[tid], bb = keys[ixj];
                bool desc = ((tid & kk) == 0);
                if (desc ? (a < bb) : (a > bb)) { keys[tid] = bb; keys[ixj] = a; }
            }
        }
    }
    __syncthreads();

    // ---- phase 4: pooled outputs ----
    for (int k = w; k < KK; k += 8) {
        unsigned long long kv = keys[k];
        int r = (int)(0xFFFFFFFFu - (unsigned)(kv & 0xFFFFFFFFull));
        float v = scl[r];
        float gate = 1.f / (1.f + expf(-v));
        float hvv = hbw[((size_t)g * NR + r)*OC + o];
        out[XP_OFF + ((size_t)g*KK + k)*64 + o] = hvv * gate;
        if (o == 0) {
            out[BP_OFF + (size_t)g*KK + k] = (float)g;
            out[PM_OFF + (size_t)g*KK + k] = (float)(g*NR + r);
        }
    }
}

// ---------------------------------------------------------------------------
extern "C" void kernel_launch(void* const* d_in, const int* in_sizes, int n_in,
                              void* d_out, int out_size, void* d_ws, size_t ws_size,
                              hipStream_t stream) {
    const float* x     = (const float*)d_in[0];
    const int*   ei    = (const int*)d_in[1];
    const float* ea    = (const float*)d_in[2];
    // d_in[3] batch: structurally known (g = n / NR), unused
    const float* basis = (const float*)d_in[4];
    const float* rc    = (const float*)d_in[5];
    const float* ew_w  = (const float*)d_in[6];
    const float* ew_b  = (const float*)d_in[7];
    const float* cbias = (const float*)d_in[8];
    const float* ln_g  = (const float*)d_in[9];
    const float* ln_b  = (const float*)d_in[10];
    const float* w1    = (const float*)d_in[11];
    const float* b1    = (const float*)d_in[12];
    const float* w2    = (const float*)d_in[13];
    const float* b2    = (const float*)d_in[14];
    float* out = (float*)d_out;

    float* wsf = (float*)d_ws;
    float* roik = wsf + WS_ROIK;
    float* xt   = wsf + WS_XT;
    float* hbw  = wsf + WS_HB;
    float2* meta = (float2*)(wsf + WS_META);
    unsigned int* rows = (unsigned int*)(wsf + WS_ROWS);

    k_roik<<<dim3(NR), dim3(256), 0, stream>>>(rc, basis, roik);
    k_xt  <<<dim3(NR), dim3(256), 0, stream>>>(x, roik, xt);
    k_csr <<<dim3(NB), dim3(256), 0, stream>>>(ei, ea, meta, rows);
    k_main<<<dim3(NB), dim3(512), 0, stream>>>(xt, meta, rows, hbw,
                                               ew_w, ew_b, cbias, ln_g, ln_b,
                                               w1, b1, w2, b2, out);
}

// Round 2
// 454.272 us; speedup vs baseline: 1.1377x; 1.1377x over previous
//
#include <hip/hip_runtime.h>
#include <cstdint>
#include <cstddef>

// Problem constants (fixed by reference)
#define NR   268
#define NB   256
#define NN   (NR*NB)        // 68608 nodes
#define IC   256
#define OC   64
#define DEG  32
#define EPG  (NR*DEG)       // 8576 edges per graph
#define NE   (NN*DEG)       // 2195456 edges
#define KK   214            // top-k per graph

// d_out layout (floats, concatenated outputs)
#define XP_OFF 0            // x_pooled  (256*214, 64)
#define BP_OFF 3506176      // batch_pooled (256*214)
#define SC_OFF 3560960      // scores (68608)
#define PM_OFF 3629568      // perm (256*214)

// workspace layout (float offsets)
#define WS_ROIK 0           // 268*256*64
#define WS_XT   4390912     // 68608*64
#define WS_HB   8781824     // 68608*64  (ELU'd v, then LN'd h in place)
#define WS_META 13172736    // E float2 = 2E floats (src,attr in CSR-by-dst order)
#define WS_ROWS 17563648    // 256*(268+1) uint32 row starts

// ---------------------------------------------------------------------------
// K1: cw = softmax(roi_community); roi_k[r] = sum_c cw[c] * basis[c]
// ---------------------------------------------------------------------------
__global__ __launch_bounds__(256) void k_roik(const float* __restrict__ rc,
                                              const float* __restrict__ basis,
                                              float* __restrict__ roik) {
    int r = blockIdx.x;
    float c[7];
    float m = -1e30f;
#pragma unroll
    for (int j = 0; j < 7; ++j) { c[j] = rc[r*7 + j]; m = fmaxf(m, c[j]); }
    float s = 0.f;
#pragma unroll
    for (int j = 0; j < 7; ++j) { c[j] = expf(c[j] - m); s += c[j]; }
    float inv = 1.f / s;
#pragma unroll
    for (int j = 0; j < 7; ++j) c[j] *= inv;
    for (int idx = threadIdx.x; idx < IC*OC; idx += 256) {
        float acc = 0.f;
#pragma unroll
        for (int j = 0; j < 7; ++j) acc = fmaf(c[j], basis[j*IC*OC + idx], acc);
        roik[(size_t)r*IC*OC + idx] = acc;
    }
}

// ---------------------------------------------------------------------------
// K2: xt[n] = x[n] @ roi_k[n%NR].  Register-tiled LDS GEMM.
// block = ROI r. 256 threads = 32 g-groups x 8 o-groups; thread tile 8g x 8o.
// X tile transposed in LDS (stride 264 breaks power-of-2), W tile row-major.
// ---------------------------------------------------------------------------
#define KT   32
#define XSTR 264
__global__ __launch_bounds__(256, 1) void k_xt(const float* __restrict__ x,
                                               const float* __restrict__ roik,
                                               float* __restrict__ xt) {
    __shared__ float sXT[KT * XSTR];   // [k][g] transposed, 33792 B
    __shared__ float sWT[KT * OC];     // [k][o] row-major,    8192 B

    int r = blockIdx.x;
    int tid = threadIdx.x;
    int g0 = (tid & 31) * 8;           // graph tile base
    int o0 = (tid >> 5) * 8;           // out-channel tile base

    const float* __restrict__ xrow = x + ((size_t)tid * NR + r) * IC; // stager: thread t owns graph t's row
    const float* __restrict__ wk = roik + (size_t)r * (IC*OC);

    float acc[8][8];
#pragma unroll
    for (int i = 0; i < 8; ++i)
#pragma unroll
        for (int j = 0; j < 8; ++j) acc[i][j] = 0.f;

    for (int kt = 0; kt < IC; kt += KT) {
        __syncthreads();
        // stage X: thread t loads 32 floats of graph t's row, writes transposed
#pragma unroll
        for (int u = 0; u < KT; u += 4) {
            float4 xv = *(const float4*)(xrow + kt + u);
            sXT[(u+0)*XSTR + tid] = xv.x;
            sXT[(u+1)*XSTR + tid] = xv.y;
            sXT[(u+2)*XSTR + tid] = xv.z;
            sXT[(u+3)*XSTR + tid] = xv.w;
        }
        // stage W: 2048 floats = 512 float4, 2 per thread, coalesced
        {
            const float4* wsrc = (const float4*)(wk + (size_t)kt * OC);
            ((float4*)sWT)[tid*2]   = wsrc[tid*2];
            ((float4*)sWT)[tid*2+1] = wsrc[tid*2+1];
        }
        __syncthreads();

#pragma unroll 4
        for (int k = 0; k < KT; ++k) {
            const float4* xa = (const float4*)&sXT[k*XSTR + g0];
            const float4* wa = (const float4*)&sWT[k*OC  + o0];
            float4 x4a = xa[0], x4b = xa[1];
            float4 w4a = wa[0], w4b = wa[1];
            float xg[8] = {x4a.x,x4a.y,x4a.z,x4a.w, x4b.x,x4b.y,x4b.z,x4b.w};
            float wv[8] = {w4a.x,w4a.y,w4a.z,w4a.w, w4b.x,w4b.y,w4b.z,w4b.w};
#pragma unroll
            for (int i = 0; i < 8; ++i)
#pragma unroll
                for (int j = 0; j < 8; ++j)
                    acc[i][j] = fmaf(xg[i], wv[j], acc[i][j]);
        }
    }

    // epilogue: thread writes its 8 graphs x 8 channels
#pragma unroll
    for (int i = 0; i < 8; ++i) {
        int g = g0 + i;
        float* p = xt + ((size_t)g * NR + r) * OC + o0;
        float4 a; a.x = acc[i][0]; a.y = acc[i][1]; a.z = acc[i][2]; a.w = acc[i][3];
        float4 b; b.x = acc[i][4]; b.y = acc[i][5]; b.z = acc[i][6]; b.w = acc[i][7];
        *(float4*)p = a;
        *(float4*)(p + 4) = b;
    }
}

// ---------------------------------------------------------------------------
// K3: per-graph counting sort of edges by dst; emit (src, attr) in CSR order.
// ---------------------------------------------------------------------------
__global__ __launch_bounds__(256) void k_csr(const int* __restrict__ ei,
                                             const float* __restrict__ ea,
                                             float2* __restrict__ meta,
                                             unsigned int* __restrict__ rows) {
    int g = blockIdx.x;
    __shared__ unsigned int cnt[NR];
    __shared__ unsigned int rs[NR];
    __shared__ unsigned int cur[NR];
    for (int i = threadIdx.x; i < NR; i += 256) cnt[i] = 0u;
    __syncthreads();
    int ebase = g * EPG;
    for (int e = threadIdx.x; e < EPG; e += 256) {
        int ld = ei[NE + ebase + e] - g * NR;
        atomicAdd(&cnt[ld], 1u);
    }
    __syncthreads();
    if (threadIdx.x < 64) {                  // wave 0: exclusive scan of 268
        unsigned run = 0;
        for (int base = 0; base < NR; base += 64) {
            int idx = base + (int)threadIdx.x;
            unsigned v = (idx < NR) ? cnt[idx] : 0u;
            unsigned orig = v;
#pragma unroll
            for (int s = 1; s < 64; s <<= 1) {
                int t = __shfl_up((int)v, (unsigned)s, 64);
                if ((int)threadIdx.x >= s) v += (unsigned)t;
            }
            if (idx < NR) { unsigned ex = run + v - orig; rs[idx] = ex; cur[idx] = ex; }
            run += (unsigned)__shfl((int)v, 63, 64);
        }
    }
    __syncthreads();
    for (int i = threadIdx.x; i < NR + 1; i += 256)
        rows[(size_t)g * (NR + 1) + i] = (i < NR) ? rs[i] : (unsigned)EPG;
    for (int e = threadIdx.x; e < EPG; e += 256) {
        int src = ei[ebase + e];
        int dst = ei[NE + ebase + e];
        float a = ea[ebase + e];
        int ld = dst - g * NR;
        unsigned pos = atomicAdd(&cur[ld], 1u);
        float2 mv; mv.x = __int_as_float(src); mv.y = a;
        meta[(size_t)ebase + pos] = mv;
    }
}

// sigmoid: degree-9 odd Taylor around 0, valid |z| <= 0.6 (data: |z| <= ~0.5)
__device__ __forceinline__ float sgate(float z) {
    if (__builtin_expect(fabsf(z) > 0.6f, 0)) return 1.f / (1.f + expf(-z));
    float z2 = z * z;
    float p = fmaf(z2, 2.1357253e-5f, -2.1081349e-4f);  // c9, c7
    p = fmaf(z2, p, 2.0833333e-3f);                     // c5
    p = fmaf(z2, p, -2.0833334e-2f);                    // c3
    p = fmaf(z2, p, 0.25f);                             // c1
    return fmaf(z, p, 0.5f);
}

// ---------------------------------------------------------------------------
// K4: aggregation + bias + ELU.  grid = 1024 = (q-chunk, graph); bid%256 = g
// so all 4 chunks of a graph land on the same XCD (bid%8 == g%8).
// 67 rows per chunk. lane = channel o; wave = row walker; unroll-8 edge loop.
// ---------------------------------------------------------------------------
__global__ __launch_bounds__(256) void k_agg(
    const float* __restrict__ xt,
    const float2* __restrict__ meta,
    const unsigned int* __restrict__ rows,
    float* __restrict__ hbw,
    const float* __restrict__ ew_w, const float* __restrict__ ew_b,
    const float* __restrict__ conv_bias)
{
    int bid = blockIdx.x;
    int g = bid & 255;
    int q = bid >> 8;                     // 0..3
    int tid = threadIdx.x;
    int o = tid & 63, w = tid >> 6;       // 4 waves

    float wo = ew_w[o], bo = ew_b[o], cb = conv_bias[o];
    float sgself = 1.f / (1.f + expf(-(wo + bo)));

    const float2* __restrict__ gm = meta + (size_t)g * EPG;
    const unsigned int* __restrict__ gr = rows + (size_t)g * (NR + 1);
    int rbase = q * 67;

    for (int r = rbase + w; r < rbase + 67; r += 4) {
        size_t n = (size_t)g * NR + r;
        unsigned js = gr[r], je = gr[r + 1];
        float acc = xt[n*OC + o] * sgself;     // self loop (attr = 1)
        unsigned j = js;
        for (; j + 8 <= je; j += 8) {
            float2 m0 = gm[j],   m1 = gm[j+1], m2 = gm[j+2], m3 = gm[j+3];
            float2 m4 = gm[j+4], m5 = gm[j+5], m6 = gm[j+6], m7 = gm[j+7];
            float x0 = xt[(size_t)__float_as_int(m0.x)*OC + o];
            float x1 = xt[(size_t)__float_as_int(m1.x)*OC + o];
            float x2 = xt[(size_t)__float_as_int(m2.x)*OC + o];
            float x3 = xt[(size_t)__float_as_int(m3.x)*OC + o];
            float x4 = xt[(size_t)__float_as_int(m4.x)*OC + o];
            float x5 = xt[(size_t)__float_as_int(m5.x)*OC + o];
            float x6 = xt[(size_t)__float_as_int(m6.x)*OC + o];
            float x7 = xt[(size_t)__float_as_int(m7.x)*OC + o];
            acc = fmaf(x0, sgate(fmaf(m0.y, wo, bo)), acc);
            acc = fmaf(x1, sgate(fmaf(m1.y, wo, bo)), acc);
            acc = fmaf(x2, sgate(fmaf(m2.y, wo, bo)), acc);
            acc = fmaf(x3, sgate(fmaf(m3.y, wo, bo)), acc);
            acc = fmaf(x4, sgate(fmaf(m4.y, wo, bo)), acc);
            acc = fmaf(x5, sgate(fmaf(m5.y, wo, bo)), acc);
            acc = fmaf(x6, sgate(fmaf(m6.y, wo, bo)), acc);
            acc = fmaf(x7, sgate(fmaf(m7.y, wo, bo)), acc);
        }
        for (; j < je; ++j) {
            float2 m = gm[j];
            float xv = xt[(size_t)__float_as_int(m.x)*OC + o];
            acc = fmaf(xv, sgate(fmaf(m.y, wo, bo)), acc);
        }
        acc += cb;
        hbw[n*OC + o] = acc > 0.f ? acc : expm1f(acc);   // ELU (alpha=1)
    }
}

// ---------------------------------------------------------------------------
// K5: per-graph LN + attention scores (wave-per-node, no spills) ->
//     bitonic top-214 -> pooled outputs.  256 blocks x 512 threads.
// ---------------------------------------------------------------------------
__global__ __launch_bounds__(512) void k_post(
    float* __restrict__ hbw,
    const float* __restrict__ ln_g, const float* __restrict__ ln_b,
    const float* __restrict__ w1, const float* __restrict__ b1,
    const float* __restrict__ w2, const float* __restrict__ b2,
    float* __restrict__ out)
{
    __shared__ float scl[NR];
    __shared__ unsigned long long keys[512];

    int g = blockIdx.x;
    int tid = threadIdx.x;
    int o = tid & 63, w = tid >> 6;          // 8 waves

    float lng = ln_g[o], lnb = ln_b[o];
    float w2o = w2[o], b1o = b1[o], b2s = b2[0];

    // ---- phase A: LN + score, one wave per node, state in lane registers ----
    for (int r = w; r < NR; r += 8) {
        size_t n = (size_t)g * NR + r;
        float v = hbw[n*OC + o];
        // mean
        float s1 = v;
#pragma unroll
        for (int m = 1; m < 64; m <<= 1) s1 += __shfl_xor(s1, m, 64);
        float mu = s1 * (1.f/64.f);
        float d = v - mu;
        float s2 = d * d;
#pragma unroll
        for (int m = 1; m < 64; m <<= 1) s2 += __shfl_xor(s2, m, 64);
        float rsd = rsqrtf(s2 * (1.f/64.f) + 1e-5f);
        float h = fmaf(d * rsd, lng, lnb);
        hbw[n*OC + o] = h;
        // t_o = b1[o] + sum_i h_i * w1[i][o]
        float t = b1o;
#pragma unroll 8
        for (int i = 0; i < 64; ++i) {
            float hb = __shfl(h, i, 64);
            t = fmaf(hb, w1[i*OC + o], t);
        }
        // tanh, dot with w2
        float a2 = fminf(fmaxf(2.f * t, -80.f), 80.f);
        float y = expf(a2);
        float th = (y - 1.f) / (y + 1.f);
        float p = th * w2o;
#pragma unroll
        for (int m = 1; m < 64; m <<= 1) p += __shfl_xor(p, m, 64);
        float sc = p + b2s;
        if (o == 0) {
            scl[r] = sc;
            out[SC_OFF + (size_t)g * NR + r] = sc;
        }
    }
    __syncthreads();

    // ---- phase B: bitonic top-K. key = ordered(score) << 32 | ~index ----
    {
        unsigned long long key = 0ull;
        if (tid < NR) {
            unsigned ub = __float_as_uint(scl[tid]);
            unsigned ou = (ub & 0x80000000u) ? ~ub : (ub | 0x80000000u);
            key = (((unsigned long long)ou) << 32) |
                  (unsigned long long)(0xFFFFFFFFu - (unsigned)tid);
        }
        keys[tid] = key;
    }
    for (int kk = 2; kk <= 512; kk <<= 1) {
        for (int j = kk >> 1; j > 0; j >>= 1) {
            __syncthreads();
            int ixj = tid ^ j;
            if (ixj > tid) {
                unsigned long long a = keys[tid], bb = keys[ixj];
                bool desc = ((tid & kk) == 0);
                if (desc ? (a < bb) : (a > bb)) { keys[tid] = bb; keys[ixj] = a; }
            }
        }
    }
    __syncthreads();

    // ---- phase C: pooled outputs ----
    for (int k = w; k < KK; k += 8) {
        unsigned long long kv = keys[k];
        int r = (int)(0xFFFFFFFFu - (unsigned)(kv & 0xFFFFFFFFull));
        float v = scl[r];
        float gate = 1.f / (1.f + expf(-v));
        float hvv = hbw[((size_t)g * NR + r)*OC + o];
        out[XP_OFF + ((size_t)g*KK + k)*64 + o] = hvv * gate;
        if (o == 0) {
            out[BP_OFF + (size_t)g*KK + k] = (float)g;
            out[PM_OFF + (size_t)g*KK + k] = (float)(g*NR + r);
        }
    }
}

// ---------------------------------------------------------------------------
extern "C" void kernel_launch(void* const* d_in, const int* in_sizes, int n_in,
                              void* d_out, int out_size, void* d_ws, size_t ws_size,
                              hipStream_t stream) {
    const float* x     = (const float*)d_in[0];
    const int*   ei    = (const int*)d_in[1];
    const float* ea    = (const float*)d_in[2];
    // d_in[3] batch: structurally known (g = n / NR), unused
    const float* basis = (const float*)d_in[4];
    const float* rc    = (const float*)d_in[5];
    const float* ew_w  = (const float*)d_in[6];
    const float* ew_b  = (const float*)d_in[7];
    const float* cbias = (const float*)d_in[8];
    const float* ln_g  = (const float*)d_in[9];
    const float* ln_b  = (const float*)d_in[10];
    const float* w1    = (const float*)d_in[11];
    const float* b1    = (const float*)d_in[12];
    const float* w2    = (const float*)d_in[13];
    const float* b2    = (const float*)d_in[14];
    float* out = (float*)d_out;

    float* wsf = (float*)d_ws;
    float* roik = wsf + WS_ROIK;
    float* xtb  = wsf + WS_XT;
    float* hbw  = wsf + WS_HB;
    float2* meta = (float2*)(wsf + WS_META);
    unsigned int* rows = (unsigned int*)(wsf + WS_ROWS);

    k_roik<<<dim3(NR), dim3(256), 0, stream>>>(rc, basis, roik);
    k_xt  <<<dim3(NR), dim3(256), 0, stream>>>(x, roik, xtb);
    k_csr <<<dim3(NB), dim3(256), 0, stream>>>(ei, ea, meta, rows);
    k_agg <<<dim3(1024), dim3(256), 0, stream>>>(xtb, meta, rows, hbw,
                                                 ew_w, ew_b, cbias);
    k_post<<<dim3(NB), dim3(512), 0, stream>>>(hbw, ln_g, ln_b,
                                               w1, b1, w2, b2, out);
}

// Round 3
// 410.744 us; speedup vs baseline: 1.2582x; 1.1060x over previous
//
#include <hip/hip_runtime.h>
#include <cstdint>
#include <cstddef>

// Problem constants (fixed by reference)
#define NR   268
#define NB   256
#define NN   (NR*NB)        // 68608 nodes
#define IC   256
#define OC   64
#define DEG  32
#define EPG  (NR*DEG)       // 8576 edges per graph
#define NE   (NN*DEG)       // 2195456 edges
#define KK   214            // top-k per graph

// d_out layout (floats, concatenated outputs)
#define XP_OFF 0            // x_pooled  (256*214, 64)
#define BP_OFF 3506176      // batch_pooled (256*214)
#define SC_OFF 3560960      // scores (68608)
#define PM_OFF 3629568      // perm (256*214)

// workspace layout (float offsets)
#define WS_XT   4390912     // 68608*64
#define WS_HB   8781824     // 68608*64  (post-LN h)
#define WS_META 13172736    // E float2 = 2E floats (src*64, attr) CSR-by-dst
#define WS_ROWS 17563648    // 256*(268+1) uint32 row starts

// ---------------------------------------------------------------------------
// K1: fused roi_k build + per-node transform.
// xt[n] = x[n] @ (softmax(rc[r]) . basis)   for n = g*NR + r.
// grid = 268 ROIs x 2 graph-halves. block 256 thr; thread tile 4g x 8o.
// W tile computed from basis in LDS each k-tile (adds ~5% FMA, kills k_roik).
// ---------------------------------------------------------------------------
#define KT   32
#define GS   132            // sX row stride (floats), %4==0 for b128 alignment
__global__ __launch_bounds__(256) void k_xtf(const float* __restrict__ x,
                                             const float* __restrict__ basis,
                                             const float* __restrict__ rc,
                                             float* __restrict__ xt) {
    __shared__ float sX[KT * GS];      // [k][g] transposed  (16.9 KB)
    __shared__ float sW[KT * OC];      // [k][o]             (8 KB)

    int bid = blockIdx.x;
    int r = bid % NR;
    int half = bid / NR;               // 0 or 1 (graphs 0..127 / 128..255)
    int tid = threadIdx.x;
    int gl4 = (tid & 31) * 4;          // local graph tile base (0..124)
    int o0  = (tid >> 5) * 8;          // out-channel tile base

    // softmax(rc[r]) in registers (wave-uniform -> s_loads)
    float cw[7];
    {
        float m = -1e30f;
#pragma unroll
        for (int j = 0; j < 7; ++j) { cw[j] = rc[r*7 + j]; m = fmaxf(m, cw[j]); }
        float s = 0.f;
#pragma unroll
        for (int j = 0; j < 7; ++j) { cw[j] = expf(cw[j] - m); s += cw[j]; }
        float inv = 1.f / s;
#pragma unroll
        for (int j = 0; j < 7; ++j) cw[j] *= inv;
    }

    // X stager: thread t owns local graph (t&127), k-segment (t>>7)*16
    int sg = tid & 127, kseg = (tid >> 7) * 16;
    const float* __restrict__ xrow =
        x + ((size_t)(half*128 + sg) * NR + r) * IC + kseg;
    // W builder: thread t owns sW[tid*8 .. tid*8+7]
    int wk_ = tid >> 3, wo_ = (tid & 7) * 8;
    const float* __restrict__ bb = basis + (size_t)wk_ * OC + wo_;

    float acc[4][8];
#pragma unroll
    for (int i = 0; i < 4; ++i)
#pragma unroll
        for (int j = 0; j < 8; ++j) acc[i][j] = 0.f;

    for (int kt = 0; kt < IC; kt += KT) {
        __syncthreads();
        // stage X transposed
#pragma unroll
        for (int u = 0; u < 16; u += 4) {
            float4 xv = *(const float4*)(xrow + kt + u);
            sX[(kseg+u+0)*GS + sg] = xv.x;
            sX[(kseg+u+1)*GS + sg] = xv.y;
            sX[(kseg+u+2)*GS + sg] = xv.z;
            sX[(kseg+u+3)*GS + sg] = xv.w;
        }
        // build W tile: sW[k][o] = sum_c cw[c]*basis[c][kt+k][o]
        {
            const float* bp = bb + (size_t)kt * OC;
            float4 a = {0,0,0,0}, b = {0,0,0,0};
#pragma unroll
            for (int c = 0; c < 7; ++c) {
                float4 ba = *(const float4*)(bp + (size_t)c * (IC*OC));
                float4 bbv = *(const float4*)(bp + (size_t)c * (IC*OC) + 4);
                a.x = fmaf(cw[c], ba.x, a.x);  a.y = fmaf(cw[c], ba.y, a.y);
                a.z = fmaf(cw[c], ba.z, a.z);  a.w = fmaf(cw[c], ba.w, a.w);
                b.x = fmaf(cw[c], bbv.x, b.x); b.y = fmaf(cw[c], bbv.y, b.y);
                b.z = fmaf(cw[c], bbv.z, b.z); b.w = fmaf(cw[c], bbv.w, b.w);
            }
            *(float4*)&sW[tid*8]     = a;
            *(float4*)&sW[tid*8 + 4] = b;
        }
        __syncthreads();

#pragma unroll 4
        for (int k = 0; k < KT; ++k) {
            float4 xv = *(const float4*)&sX[k*GS + gl4];
            const float4* wp = (const float4*)&sW[k*OC + o0];
            float4 wa = wp[0], wb = wp[1];
            float xg[4] = {xv.x, xv.y, xv.z, xv.w};
            float wv[8] = {wa.x,wa.y,wa.z,wa.w, wb.x,wb.y,wb.z,wb.w};
#pragma unroll
            for (int i = 0; i < 4; ++i)
#pragma unroll
                for (int j = 0; j < 8; ++j)
                    acc[i][j] = fmaf(xg[i], wv[j], acc[i][j]);
        }
    }

#pragma unroll
    for (int i = 0; i < 4; ++i) {
        int g = half*128 + gl4 + i;
        float* p = xt + ((size_t)g * NR + r) * OC + o0;
        float4 a; a.x = acc[i][0]; a.y = acc[i][1]; a.z = acc[i][2]; a.w = acc[i][3];
        float4 b; b.x = acc[i][4]; b.y = acc[i][5]; b.z = acc[i][6]; b.w = acc[i][7];
        *(float4*)p = a;
        *(float4*)(p + 4) = b;
    }
}

// ---------------------------------------------------------------------------
// K2: per-graph counting sort of edges by dst; emit (src*64, attr) CSR order.
// ---------------------------------------------------------------------------
__global__ __launch_bounds__(512) void k_csr(const int* __restrict__ ei,
                                             const float* __restrict__ ea,
                                             float2* __restrict__ meta,
                                             unsigned int* __restrict__ rows) {
    int g = blockIdx.x;
    __shared__ unsigned int cnt[NR];
    __shared__ unsigned int rs[NR];
    __shared__ unsigned int cur[NR];
    for (int i = threadIdx.x; i < NR; i += 512) cnt[i] = 0u;
    __syncthreads();
    int ebase = g * EPG;
    for (int e = threadIdx.x; e < EPG; e += 512) {
        int ld = ei[NE + ebase + e] - g * NR;
        atomicAdd(&cnt[ld], 1u);
    }
    __syncthreads();
    if (threadIdx.x < 64) {                  // wave 0: exclusive scan of 268
        unsigned run = 0;
        for (int base = 0; base < NR; base += 64) {
            int idx = base + (int)threadIdx.x;
            unsigned v = (idx < NR) ? cnt[idx] : 0u;
            unsigned orig = v;
#pragma unroll
            for (int s = 1; s < 64; s <<= 1) {
                int t = __shfl_up((int)v, (unsigned)s, 64);
                if ((int)threadIdx.x >= s) v += (unsigned)t;
            }
            if (idx < NR) { unsigned ex = run + v - orig; rs[idx] = ex; cur[idx] = ex; }
            run += (unsigned)__shfl((int)v, 63, 64);
        }
    }
    __syncthreads();
    for (int i = threadIdx.x; i < NR + 1; i += 512)
        rows[(size_t)g * (NR + 1) + i] = (i < NR) ? rs[i] : (unsigned)EPG;
    for (int e = threadIdx.x; e < EPG; e += 512) {
        int src = ei[ebase + e];
        int dst = ei[NE + ebase + e];
        float a = ea[ebase + e];
        int ld = dst - g * NR;
        unsigned pos = atomicAdd(&cur[ld], 1u);
        float2 mv; mv.x = __int_as_float(src * OC); mv.y = a;
        meta[(size_t)ebase + pos] = mv;
    }
}

// sigmoid: degree-9 odd Taylor around 0, valid |z| <= 0.6 (data: |z| <= ~0.5)
__device__ __forceinline__ float sgate(float z) {
    if (__builtin_expect(fabsf(z) > 0.6f, 0)) return 1.f / (1.f + expf(-z));
    float z2 = z * z;
    float p = fmaf(z2, 2.1357253e-5f, -2.1081349e-4f);  // c9, c7
    p = fmaf(z2, p, 2.0833333e-3f);                     // c5
    p = fmaf(z2, p, -2.0833334e-2f);                    // c3
    p = fmaf(z2, p, 0.25f);                             // c1
    return fmaf(z, p, 0.5f);
}

// ---------------------------------------------------------------------------
// K3: aggregation + bias + ELU + LayerNorm (row lives in one wave's lanes).
// grid = 2048 = 8 row-chunks x 256 graphs; bid&255 = g so all chunks of a
// graph share an XCD (bid%8 == g%8). 34 rows/chunk, 4 waves walk them.
// ---------------------------------------------------------------------------
__global__ __launch_bounds__(256, 6) void k_agg(
    const float* __restrict__ xt,
    const float2* __restrict__ meta,
    const unsigned int* __restrict__ rows,
    float* __restrict__ hbw,
    const float* __restrict__ ew_w, const float* __restrict__ ew_b,
    const float* __restrict__ conv_bias,
    const float* __restrict__ ln_g, const float* __restrict__ ln_b)
{
    int bid = blockIdx.x;
    int g = bid & 255;
    int q = bid >> 8;                     // 0..7
    int tid = threadIdx.x;
    int o = tid & 63, w = tid >> 6;       // 4 waves

    float wo = ew_w[o], bo = ew_b[o], cb = conv_bias[o];
    float lng = ln_g[o], lnb = ln_b[o];
    float sgself = 1.f / (1.f + expf(-(wo + bo)));

    const float2* __restrict__ gm = meta + (size_t)g * EPG;
    const unsigned int* __restrict__ gr = rows + (size_t)g * (NR + 1);
    int rbase = q * 34;
    int rend = rbase + 34; if (rend > NR) rend = NR;

    for (int r = rbase + w; r < rend; r += 4) {
        unsigned nb = (unsigned)g * NR + (unsigned)r;
        unsigned js = gr[r], je = gr[r + 1];
        float acc = xt[nb*OC + o] * sgself;    // self loop (attr = 1)
        unsigned j = js;
        for (; j + 8 <= je; j += 8) {
            float2 m0 = gm[j],   m1 = gm[j+1], m2 = gm[j+2], m3 = gm[j+3];
            float2 m4 = gm[j+4], m5 = gm[j+5], m6 = gm[j+6], m7 = gm[j+7];
            float x0 = xt[(unsigned)(__float_as_int(m0.x) + o)];
            float x1 = xt[(unsigned)(__float_as_int(m1.x) + o)];
            float x2 = xt[(unsigned)(__float_as_int(m2.x) + o)];
            float x3 = xt[(unsigned)(__float_as_int(m3.x) + o)];
            float x4 = xt[(unsigned)(__float_as_int(m4.x) + o)];
            float x5 = xt[(unsigned)(__float_as_int(m5.x) + o)];
            float x6 = xt[(unsigned)(__float_as_int(m6.x) + o)];
            float x7 = xt[(unsigned)(__float_as_int(m7.x) + o)];
            acc = fmaf(x0, sgate(fmaf(m0.y, wo, bo)), acc);
            acc = fmaf(x1, sgate(fmaf(m1.y, wo, bo)), acc);
            acc = fmaf(x2, sgate(fmaf(m2.y, wo, bo)), acc);
            acc = fmaf(x3, sgate(fmaf(m3.y, wo, bo)), acc);
            acc = fmaf(x4, sgate(fmaf(m4.y, wo, bo)), acc);
            acc = fmaf(x5, sgate(fmaf(m5.y, wo, bo)), acc);
            acc = fmaf(x6, sgate(fmaf(m6.y, wo, bo)), acc);
            acc = fmaf(x7, sgate(fmaf(m7.y, wo, bo)), acc);
        }
        for (; j < je; ++j) {
            float2 m = gm[j];
            float xv = xt[(unsigned)(__float_as_int(m.x) + o)];
            acc = fmaf(xv, sgate(fmaf(m.y, wo, bo)), acc);
        }
        acc += cb;
        float v = acc > 0.f ? acc : expm1f(acc);   // ELU (alpha=1)
        // LayerNorm across the wave's 64 lanes
        float s1 = v;
#pragma unroll
        for (int m = 1; m < 64; m <<= 1) s1 += __shfl_xor(s1, m, 64);
        float mu = s1 * (1.f/64.f);
        float d = v - mu;
        float s2 = d * d;
#pragma unroll
        for (int m = 1; m < 64; m <<= 1) s2 += __shfl_xor(s2, m, 64);
        float rsd = rsqrtf(s2 * (1.f/64.f) + 1e-5f);
        hbw[(size_t)nb*OC + o] = fmaf(d * rsd, lng, lnb);
    }
}

// ---------------------------------------------------------------------------
// K4: attention scores (w1 column in 64 VGPRs, readlane broadcasts) ->
//     bitonic top-214 -> pooled outputs.  256 blocks x 512 threads.
// ---------------------------------------------------------------------------
__global__ __launch_bounds__(512) void k_post(
    const float* __restrict__ hbw,
    const float* __restrict__ w1, const float* __restrict__ b1,
    const float* __restrict__ w2, const float* __restrict__ b2,
    float* __restrict__ out)
{
    __shared__ float scl[NR];
    __shared__ unsigned long long keys[512];

    int g = blockIdx.x;
    int tid = threadIdx.x;
    int o = tid & 63, w = tid >> 6;          // 8 waves

    float w2o = w2[o], b1o = b1[o], b2s = b2[0];
    float w1c[64];
#pragma unroll
    for (int i = 0; i < 64; ++i) w1c[i] = w1[i*OC + o];   // column o of W1

    // ---- phase A: scores, one wave per node ----
    for (int r = w; r < NR; r += 8) {
        size_t n = (size_t)g * NR + r;
        float h = hbw[n*OC + o];
        float t = b1o;
#pragma unroll
        for (int i = 0; i < 64; ++i)
            t = fmaf(__shfl(h, i, 64), w1c[i], t);
        float a2 = fminf(fmaxf(2.f * t, -80.f), 80.f);
        float y = expf(a2);
        float th = (y - 1.f) / (y + 1.f);
        float p = th * w2o;
#pragma unroll
        for (int m = 1; m < 64; m <<= 1) p += __shfl_xor(p, m, 64);
        float sc = p + b2s;
        if (o == 0) {
            scl[r] = sc;
            out[SC_OFF + (size_t)g * NR + r] = sc;
        }
    }
    __syncthreads();

    // ---- phase B: bitonic top-K. key = ordered(score) << 32 | ~index ----
    {
        unsigned long long key = 0ull;
        if (tid < NR) {
            unsigned ub = __float_as_uint(scl[tid]);
            unsigned ou = (ub & 0x80000000u) ? ~ub : (ub | 0x80000000u);
            key = (((unsigned long long)ou) << 32) |
                  (unsigned long long)(0xFFFFFFFFu - (unsigned)tid);
        }
        keys[tid] = key;
    }
    for (int kk = 2; kk <= 512; kk <<= 1) {
        for (int j = kk >> 1; j > 0; j >>= 1) {
            __syncthreads();
            int ixj = tid ^ j;
            if (ixj > tid) {
                unsigned long long a = keys[tid], bb = keys[ixj];
                bool desc = ((tid & kk) == 0);
                if (desc ? (a < bb) : (a > bb)) { keys[tid] = bb; keys[ixj] = a; }
            }
        }
    }
    __syncthreads();

    // ---- phase C: pooled outputs ----
    for (int k = w; k < KK; k += 8) {
        unsigned long long kv = keys[k];
        int r = (int)(0xFFFFFFFFu - (unsigned)(kv & 0xFFFFFFFFull));
        float v = scl[r];
        float gate = 1.f / (1.f + expf(-v));
        float hvv = hbw[((size_t)g * NR + r)*OC + o];
        out[XP_OFF + ((size_t)g*KK + k)*64 + o] = hvv * gate;
        if (o == 0) {
            out[BP_OFF + (size_t)g*KK + k] = (float)g;
            out[PM_OFF + (size_t)g*KK + k] = (float)(g*NR + r);
        }
    }
}

// ---------------------------------------------------------------------------
extern "C" void kernel_launch(void* const* d_in, const int* in_sizes, int n_in,
                              void* d_out, int out_size, void* d_ws, size_t ws_size,
                              hipStream_t stream) {
    const float* x     = (const float*)d_in[0];
    const int*   ei    = (const int*)d_in[1];
    const float* ea    = (const float*)d_in[2];
    // d_in[3] batch: structurally known (g = n / NR), unused
    const float* basis = (const float*)d_in[4];
    const float* rc    = (const float*)d_in[5];
    const float* ew_w  = (const float*)d_in[6];
    const float* ew_b  = (const float*)d_in[7];
    const float* cbias = (const float*)d_in[8];
    const float* ln_g  = (const float*)d_in[9];
    const float* ln_b  = (const float*)d_in[10];
    const float* w1    = (const float*)d_in[11];
    const float* b1    = (const float*)d_in[12];
    const float* w2    = (const float*)d_in[13];
    const float* b2    = (const float*)d_in[14];
    float* out = (float*)d_out;

    float* wsf = (float*)d_ws;
    float* xtb  = wsf + WS_XT;
    float* hbw  = wsf + WS_HB;
    float2* meta = (float2*)(wsf + WS_META);
    unsigned int* rows = (unsigned int*)(wsf + WS_ROWS);

    k_xtf <<<dim3(NR*2), dim3(256), 0, stream>>>(x, basis, rc, xtb);
    k_csr <<<dim3(NB),   dim3(512), 0, stream>>>(ei, ea, meta, rows);
    k_agg <<<dim3(2048), dim3(256), 0, stream>>>(xtb, meta, rows, hbw,
                                                 ew_w, ew_b, cbias, ln_g, ln_b);
    k_post<<<dim3(NB),   dim3(512), 0, stream>>>(hbw, w1, b1, w2, b2, out);
}

// Round 4
// 378.838 us; speedup vs baseline: 1.3642x; 1.0842x over previous
//
#include <hip/hip_runtime.h>
#include <cstdint>
#include <cstddef>

// Problem constants (fixed by reference)
#define NR   268
#define NB   256
#define NN   (NR*NB)        // 68608 nodes
#define IC   256
#define OC   64
#define DEG  32
#define EPG  (NR*DEG)       // 8576 edges per graph
#define NE   (NN*DEG)       // 2195456 edges
#define KK   214            // top-k per graph

// d_out layout (floats, concatenated outputs)
#define XP_OFF 0            // x_pooled  (256*214, 64)
#define BP_OFF 3506176      // batch_pooled (256*214)
#define SC_OFF 3560960      // scores (68608)
#define PM_OFF 3629568      // perm (256*214)

// workspace layout (float offsets)
#define WS_XT   4390912     // 68608*64
#define WS_HB   8781824     // 68608*64  (post-LN h)
#define WS_META 13172736    // E float2 = 2E floats (src*64, attr) CSR-by-dst
#define WS_ROWS 17563648    // 256*(268+1) uint32 row starts

// ---------------------------------------------------------------------------
// K1: fused roi_k build + per-node transform.
// xt[n] = x[n] @ (softmax(rc[r]) . basis)   for n = g*NR + r.
// grid = 268 ROIs x 2 graph-halves. block 256 thr; thread tile 4g x 8o.
// ---------------------------------------------------------------------------
#define KT   32
#define GS   132            // sX row stride (floats), %4==0 for b128 alignment
__global__ __launch_bounds__(256) void k_xtf(const float* __restrict__ x,
                                             const float* __restrict__ basis,
                                             const float* __restrict__ rc,
                                             float* __restrict__ xt) {
    __shared__ float sX[KT * GS];      // [k][g] transposed  (16.9 KB)
    __shared__ float sW[KT * OC];      // [k][o]             (8 KB)

    int bid = blockIdx.x;
    int r = bid % NR;
    int half = bid / NR;               // 0 or 1 (graphs 0..127 / 128..255)
    int tid = threadIdx.x;
    int gl4 = (tid & 31) * 4;          // local graph tile base (0..124)
    int o0  = (tid >> 5) * 8;          // out-channel tile base

    // softmax(rc[r]) in registers (wave-uniform -> s_loads)
    float cw[7];
    {
        float m = -1e30f;
#pragma unroll
        for (int j = 0; j < 7; ++j) { cw[j] = rc[r*7 + j]; m = fmaxf(m, cw[j]); }
        float s = 0.f;
#pragma unroll
        for (int j = 0; j < 7; ++j) { cw[j] = expf(cw[j] - m); s += cw[j]; }
        float inv = 1.f / s;
#pragma unroll
        for (int j = 0; j < 7; ++j) cw[j] *= inv;
    }

    // X stager: thread t owns local graph (t&127), k-segment (t>>7)*16
    int sg = tid & 127, kseg = (tid >> 7) * 16;
    const float* __restrict__ xrow =
        x + ((size_t)(half*128 + sg) * NR + r) * IC + kseg;
    // W builder: thread t owns sW[tid*8 .. tid*8+7]
    int wk_ = tid >> 3, wo_ = (tid & 7) * 8;
    const float* __restrict__ bb = basis + (size_t)wk_ * OC + wo_;

    float acc[4][8];
#pragma unroll
    for (int i = 0; i < 4; ++i)
#pragma unroll
        for (int j = 0; j < 8; ++j) acc[i][j] = 0.f;

    for (int kt = 0; kt < IC; kt += KT) {
        __syncthreads();
        // stage X transposed
#pragma unroll
        for (int u = 0; u < 16; u += 4) {
            float4 xv = *(const float4*)(xrow + kt + u);
            sX[(kseg+u+0)*GS + sg] = xv.x;
            sX[(kseg+u+1)*GS + sg] = xv.y;
            sX[(kseg+u+2)*GS + sg] = xv.z;
            sX[(kseg+u+3)*GS + sg] = xv.w;
        }
        // build W tile: sW[k][o] = sum_c cw[c]*basis[c][kt+k][o]
        {
            const float* bp = bb + (size_t)kt * OC;
            float4 a = {0,0,0,0}, b = {0,0,0,0};
#pragma unroll
            for (int c = 0; c < 7; ++c) {
                float4 ba = *(const float4*)(bp + (size_t)c * (IC*OC));
                float4 bbv = *(const float4*)(bp + (size_t)c * (IC*OC) + 4);
                a.x = fmaf(cw[c], ba.x, a.x);  a.y = fmaf(cw[c], ba.y, a.y);
                a.z = fmaf(cw[c], ba.z, a.z);  a.w = fmaf(cw[c], ba.w, a.w);
                b.x = fmaf(cw[c], bbv.x, b.x); b.y = fmaf(cw[c], bbv.y, b.y);
                b.z = fmaf(cw[c], bbv.z, b.z); b.w = fmaf(cw[c], bbv.w, b.w);
            }
            *(float4*)&sW[tid*8]     = a;
            *(float4*)&sW[tid*8 + 4] = b;
        }
        __syncthreads();

#pragma unroll 4
        for (int k = 0; k < KT; ++k) {
            float4 xv = *(const float4*)&sX[k*GS + gl4];
            const float4* wp = (const float4*)&sW[k*OC + o0];
            float4 wa = wp[0], wb = wp[1];
            float xg[4] = {xv.x, xv.y, xv.z, xv.w};
            float wv[8] = {wa.x,wa.y,wa.z,wa.w, wb.x,wb.y,wb.z,wb.w};
#pragma unroll
            for (int i = 0; i < 4; ++i)
#pragma unroll
                for (int j = 0; j < 8; ++j)
                    acc[i][j] = fmaf(xg[i], wv[j], acc[i][j]);
        }
    }

#pragma unroll
    for (int i = 0; i < 4; ++i) {
        int g = half*128 + gl4 + i;
        float* p = xt + ((size_t)g * NR + r) * OC + o0;
        float4 a; a.x = acc[i][0]; a.y = acc[i][1]; a.z = acc[i][2]; a.w = acc[i][3];
        float4 b; b.x = acc[i][4]; b.y = acc[i][5]; b.z = acc[i][6]; b.w = acc[i][7];
        *(float4*)p = a;
        *(float4*)(p + 4) = b;
    }
}

// ---------------------------------------------------------------------------
// K2: per-graph counting sort of edges by dst; emit (src*64, attr) CSR order.
// ---------------------------------------------------------------------------
__global__ __launch_bounds__(512) void k_csr(const int* __restrict__ ei,
                                             const float* __restrict__ ea,
                                             float2* __restrict__ meta,
                                             unsigned int* __restrict__ rows) {
    int g = blockIdx.x;
    __shared__ unsigned int cnt[NR];
    __shared__ unsigned int rs[NR];
    __shared__ unsigned int cur[NR];
    for (int i = threadIdx.x; i < NR; i += 512) cnt[i] = 0u;
    __syncthreads();
    int ebase = g * EPG;
    for (int e = threadIdx.x; e < EPG; e += 512) {
        int ld = ei[NE + ebase + e] - g * NR;
        atomicAdd(&cnt[ld], 1u);
    }
    __syncthreads();
    if (threadIdx.x < 64) {                  // wave 0: exclusive scan of 268
        unsigned run = 0;
        for (int base = 0; base < NR; base += 64) {
            int idx = base + (int)threadIdx.x;
            unsigned v = (idx < NR) ? cnt[idx] : 0u;
            unsigned orig = v;
#pragma unroll
            for (int s = 1; s < 64; s <<= 1) {
                int t = __shfl_up((int)v, (unsigned)s, 64);
                if ((int)threadIdx.x >= s) v += (unsigned)t;
            }
            if (idx < NR) { unsigned ex = run + v - orig; rs[idx] = ex; cur[idx] = ex; }
            run += (unsigned)__shfl((int)v, 63, 64);
        }
    }
    __syncthreads();
    for (int i = threadIdx.x; i < NR + 1; i += 512)
        rows[(size_t)g * (NR + 1) + i] = (i < NR) ? rs[i] : (unsigned)EPG;
    for (int e = threadIdx.x; e < EPG; e += 512) {
        int src = ei[ebase + e];
        int dst = ei[NE + ebase + e];
        float a = ea[ebase + e];
        int ld = dst - g * NR;
        unsigned pos = atomicAdd(&cur[ld], 1u);
        float2 mv; mv.x = __int_as_float(src * OC); mv.y = a;
        meta[(size_t)ebase + pos] = mv;
    }
}

// sigmoid: degree-9 odd Taylor around 0, valid |z| <= 0.6 (data: |z| <= ~0.5)
__device__ __forceinline__ float sgate(float z) {
    if (__builtin_expect(fabsf(z) > 0.6f, 0)) return 1.f / (1.f + expf(-z));
    float z2 = z * z;
    float p = fmaf(z2, 2.1357253e-5f, -2.1081349e-4f);  // c9, c7
    p = fmaf(z2, p, 2.0833333e-3f);                     // c5
    p = fmaf(z2, p, -2.0833334e-2f);                    // c3
    p = fmaf(z2, p, 0.25f);                             // c1
    return fmaf(z, p, 0.5f);
}

// ---------------------------------------------------------------------------
// K3: aggregation + bias + ELU + LayerNorm (row lives in one wave's lanes).
// grid = 2048 = 8 row-chunks x 256 graphs; bid&255 = g so all chunks of a
// graph share an XCD (bid%8 == g%8). 34 rows/chunk, 4 waves walk them.
// ---------------------------------------------------------------------------
__global__ __launch_bounds__(256, 6) void k_agg(
    const float* __restrict__ xt,
    const float2* __restrict__ meta,
    const unsigned int* __restrict__ rows,
    float* __restrict__ hbw,
    const float* __restrict__ ew_w, const float* __restrict__ ew_b,
    const float* __restrict__ conv_bias,
    const float* __restrict__ ln_g, const float* __restrict__ ln_b)
{
    int bid = blockIdx.x;
    int g = bid & 255;
    int q = bid >> 8;                     // 0..7
    int tid = threadIdx.x;
    int o = tid & 63, w = tid >> 6;       // 4 waves

    float wo = ew_w[o], bo = ew_b[o], cb = conv_bias[o];
    float lng = ln_g[o], lnb = ln_b[o];
    float sgself = 1.f / (1.f + expf(-(wo + bo)));

    const float2* __restrict__ gm = meta + (size_t)g * EPG;
    const unsigned int* __restrict__ gr = rows + (size_t)g * (NR + 1);
    int rbase = q * 34;
    int rend = rbase + 34; if (rend > NR) rend = NR;

    for (int r = rbase + w; r < rend; r += 4) {
        unsigned nb = (unsigned)g * NR + (unsigned)r;
        unsigned js = gr[r], je = gr[r + 1];
        float acc = xt[nb*OC + o] * sgself;    // self loop (attr = 1)
        unsigned j = js;
        for (; j + 8 <= je; j += 8) {
            float2 m0 = gm[j],   m1 = gm[j+1], m2 = gm[j+2], m3 = gm[j+3];
            float2 m4 = gm[j+4], m5 = gm[j+5], m6 = gm[j+6], m7 = gm[j+7];
            float x0 = xt[(unsigned)(__float_as_int(m0.x) + o)];
            float x1 = xt[(unsigned)(__float_as_int(m1.x) + o)];
            float x2 = xt[(unsigned)(__float_as_int(m2.x) + o)];
            float x3 = xt[(unsigned)(__float_as_int(m3.x) + o)];
            float x4 = xt[(unsigned)(__float_as_int(m4.x) + o)];
            float x5 = xt[(unsigned)(__float_as_int(m5.x) + o)];
            float x6 = xt[(unsigned)(__float_as_int(m6.x) + o)];
            float x7 = xt[(unsigned)(__float_as_int(m7.x) + o)];
            acc = fmaf(x0, sgate(fmaf(m0.y, wo, bo)), acc);
            acc = fmaf(x1, sgate(fmaf(m1.y, wo, bo)), acc);
            acc = fmaf(x2, sgate(fmaf(m2.y, wo, bo)), acc);
            acc = fmaf(x3, sgate(fmaf(m3.y, wo, bo)), acc);
            acc = fmaf(x4, sgate(fmaf(m4.y, wo, bo)), acc);
            acc = fmaf(x5, sgate(fmaf(m5.y, wo, bo)), acc);
            acc = fmaf(x6, sgate(fmaf(m6.y, wo, bo)), acc);
            acc = fmaf(x7, sgate(fmaf(m7.y, wo, bo)), acc);
        }
        for (; j < je; ++j) {
            float2 m = gm[j];
            float xv = xt[(unsigned)(__float_as_int(m.x) + o)];
            acc = fmaf(xv, sgate(fmaf(m.y, wo, bo)), acc);
        }
        acc += cb;
        float v = acc > 0.f ? acc : expm1f(acc);   // ELU (alpha=1)
        // LayerNorm across the wave's 64 lanes
        float s1 = v;
#pragma unroll
        for (int m = 1; m < 64; m <<= 1) s1 += __shfl_xor(s1, m, 64);
        float mu = s1 * (1.f/64.f);
        float d = v - mu;
        float s2 = d * d;
#pragma unroll
        for (int m = 1; m < 64; m <<= 1) s2 += __shfl_xor(s2, m, 64);
        float rsd = rsqrtf(s2 * (1.f/64.f) + 1e-5f);
        hbw[(size_t)nb*OC + o] = fmaf(d * rsd, lng, lnb);
    }
}

// ---------------------------------------------------------------------------
// K4: attention scores. grid = 1024 = 4 row-chunks x 256 graphs.
// __launch_bounds__(256,2) -> VGPR cap 256 so w1c[64] STAYS IN REGISTERS
// (R3's k_post capped at 64 VGPR and spilled W1 to scratch: 9.1 GB FETCH).
// ---------------------------------------------------------------------------
__global__ __launch_bounds__(256, 2) void k_score(
    const float* __restrict__ hbw,
    const float* __restrict__ w1, const float* __restrict__ b1,
    const float* __restrict__ w2, const float* __restrict__ b2,
    float* __restrict__ out)
{
    int bid = blockIdx.x;
    int g = bid & 255;
    int q = bid >> 8;                        // 0..3
    int tid = threadIdx.x;
    int o = tid & 63, w = tid >> 6;          // 4 waves

    float w2o = w2[o], b1o = b1[o], b2s = b2[0];
    float w1c[64];
#pragma unroll
    for (int i = 0; i < 64; ++i) w1c[i] = w1[i*OC + o];   // column o of W1

    int rbase = q * 67;
    for (int r = rbase + w; r < rbase + 67; r += 4) {
        size_t n = (size_t)g * NR + r;
        float h = hbw[n*OC + o];
        // t_o = b1[o] + sum_i h_i * w1[i][o]  (4 chains to hide fma latency)
        float t0 = b1o, t1 = 0.f, t2 = 0.f, t3 = 0.f;
#pragma unroll
        for (int i = 0; i < 64; i += 4) {
            t0 = fmaf(__shfl(h, i,   64), w1c[i],   t0);
            t1 = fmaf(__shfl(h, i+1, 64), w1c[i+1], t1);
            t2 = fmaf(__shfl(h, i+2, 64), w1c[i+2], t2);
            t3 = fmaf(__shfl(h, i+3, 64), w1c[i+3], t3);
        }
        float t = (t0 + t1) + (t2 + t3);
        float a2 = fminf(fmaxf(2.f * t, -80.f), 80.f);
        float y = expf(a2);
        float th = (y - 1.f) / (y + 1.f);
        float p = th * w2o;
#pragma unroll
        for (int m = 1; m < 64; m <<= 1) p += __shfl_xor(p, m, 64);
        if (o == 0) out[SC_OFF + n] = p + b2s;
    }
}

// ---------------------------------------------------------------------------
// K5: per-graph bitonic top-214 on scores -> pooled outputs.
// 256 blocks x 512 threads.
// ---------------------------------------------------------------------------
__global__ __launch_bounds__(512) void k_top(
    const float* __restrict__ hbw,
    float* __restrict__ out)
{
    __shared__ float scl[NR];
    __shared__ unsigned long long keys[512];

    int g = blockIdx.x;
    int tid = threadIdx.x;
    int o = tid & 63, w = tid >> 6;          // 8 waves

    // load scores + build keys. key = ordered(score) << 32 | ~index
    unsigned long long key = 0ull;
    if (tid < NR) {
        float sc = out[SC_OFF + (size_t)g * NR + tid];
        scl[tid] = sc;
        unsigned ub = __float_as_uint(sc);
        unsigned ou = (ub & 0x80000000u) ? ~ub : (ub | 0x80000000u);
        key = (((unsigned long long)ou) << 32) |
              (unsigned long long)(0xFFFFFFFFu - (unsigned)tid);
    }
    keys[tid] = key;

    for (int kk = 2; kk <= 512; kk <<= 1) {
        for (int j = kk >> 1; j > 0; j >>= 1) {
            __syncthreads();
            int ixj = tid ^ j;
            if (ixj > tid) {
                unsigned long long a = keys[tid], bb = keys[ixj];
                bool desc = ((tid & kk) == 0);
                if (desc ? (a < bb) : (a > bb)) { keys[tid] = bb; keys[ixj] = a; }
            }
        }
    }
    __syncthreads();

    for (int k = w; k < KK; k += 8) {
        unsigned long long kv = keys[k];
        int r = (int)(0xFFFFFFFFu - (unsigned)(kv & 0xFFFFFFFFull));
        float v = scl[r];
        float gate = 1.f / (1.f + expf(-v));
        float hvv = hbw[((size_t)g * NR + r)*OC + o];
        out[XP_OFF + ((size_t)g*KK + k)*64 + o] = hvv * gate;
        if (o == 0) {
            out[BP_OFF + (size_t)g*KK + k] = (float)g;
            out[PM_OFF + (size_t)g*KK + k] = (float)(g*NR + r);
        }
    }
}

// ---------------------------------------------------------------------------
extern "C" void kernel_launch(void* const* d_in, const int* in_sizes, int n_in,
                              void* d_out, int out_size, void* d_ws, size_t ws_size,
                              hipStream_t stream) {
    const float* x     = (const float*)d_in[0];
    const int*   ei    = (const int*)d_in[1];
    const float* ea    = (const float*)d_in[2];
    // d_in[3] batch: structurally known (g = n / NR), unused
    const float* basis = (const float*)d_in[4];
    const float* rc    = (const float*)d_in[5];
    const float* ew_w  = (const float*)d_in[6];
    const float* ew_b  = (const float*)d_in[7];
    const float* cbias = (const float*)d_in[8];
    const float* ln_g  = (const float*)d_in[9];
    const float* ln_b  = (const float*)d_in[10];
    const float* w1    = (const float*)d_in[11];
    const float* b1    = (const float*)d_in[12];
    const float* w2    = (const float*)d_in[13];
    const float* b2    = (const float*)d_in[14];
    float* out = (float*)d_out;

    float* wsf = (float*)d_ws;
    float* xtb  = wsf + WS_XT;
    float* hbw  = wsf + WS_HB;
    float2* meta = (float2*)(wsf + WS_META);
    unsigned int* rows = (unsigned int*)(wsf + WS_ROWS);

    k_xtf  <<<dim3(NR*2), dim3(256), 0, stream>>>(x, basis, rc, xtb);
    k_csr  <<<dim3(NB),   dim3(512), 0, stream>>>(ei, ea, meta, rows);
    k_agg  <<<dim3(2048), dim3(256), 0, stream>>>(xtb, meta, rows, hbw,
                                                  ew_w, ew_b, cbias, ln_g, ln_b);
    k_score<<<dim3(1024), dim3(256), 0, stream>>>(hbw, w1, b1, w2, b2, out);
    k_top  <<<dim3(NB),   dim3(512), 0, stream>>>(hbw, out);
}